// Round 2
// baseline (1996.122 us; speedup 1.0000x reference)
//
#include <hip/hip_runtime.h>
#include <math.h>

#define IN_DIM 256
#define HID 128
#define OUTD 32
#define NEG_SLOPE 0.2f

// ---------------------------------------------------------------------------
// gemm1: xs1 = x @ W1  [N,256]x[256,128], fused as1 = xs1.a_src, ad1 = xs1.a_dst
// block 128 threads = 32 colgroups x 4 rowgroups; 16 rows/block; 4x4 reg tile
// ---------------------------------------------------------------------------
__global__ __launch_bounds__(128) void gemm1_kernel(
    const float* __restrict__ x, const float* __restrict__ W1,
    const float* __restrict__ a_src, const float* __restrict__ a_dst,
    float* __restrict__ xs1, float* __restrict__ as1, float* __restrict__ ad1, int N)
{
    __shared__ float lx[16 * IN_DIM];     // 16 KB
    const int tid = threadIdx.x;
    const int row0 = blockIdx.x * 16;
    const int nrows = min(16, N - row0);

    // stage x rows (float4)
    for (int i = tid; i < nrows * (IN_DIM / 4); i += 128) {
        int r = i >> 6, q = i & 63;
        ((float4*)lx)[r * 64 + q] =
            *(const float4*)(x + (size_t)(row0 + r) * IN_DIM + q * 4);
    }
    __syncthreads();

    const int cg = tid & 31, rg = tid >> 5;
    const int c0 = cg * 4, r0 = rg * 4;
    float acc[4][4];
    #pragma unroll
    for (int i = 0; i < 4; i++)
        #pragma unroll
        for (int j = 0; j < 4; j++) acc[i][j] = 0.f;

    for (int k = 0; k < IN_DIM; k++) {
        float4 w = *(const float4*)(W1 + k * HID + c0);
        #pragma unroll
        for (int i = 0; i < 4; i++) {
            float h = lx[(r0 + i) * IN_DIM + k];
            acc[i][0] += h * w.x; acc[i][1] += h * w.y;
            acc[i][2] += h * w.z; acc[i][3] += h * w.w;
        }
    }

    // attention logits: dot acc rows with a_src/a_dst slices, reduce over 32 cg lanes
    float4 as4 = *(const float4*)(a_src + c0);
    float4 ad4 = *(const float4*)(a_dst + c0);
    #pragma unroll
    for (int i = 0; i < 4; i++) {
        float vs = acc[i][0]*as4.x + acc[i][1]*as4.y + acc[i][2]*as4.z + acc[i][3]*as4.w;
        float vd = acc[i][0]*ad4.x + acc[i][1]*ad4.y + acc[i][2]*ad4.z + acc[i][3]*ad4.w;
        #pragma unroll
        for (int off = 16; off >= 1; off >>= 1) {
            vs += __shfl_down(vs, off, 32);
            vd += __shfl_down(vd, off, 32);
        }
        if (cg == 0 && (r0 + i) < nrows) {
            as1[row0 + r0 + i] = vs;
            ad1[row0 + r0 + i] = vd;
        }
    }

    #pragma unroll
    for (int i = 0; i < 4; i++) {
        if (r0 + i < nrows) {
            float4 v; v.x = acc[i][0]; v.y = acc[i][1]; v.z = acc[i][2]; v.w = acc[i][3];
            *(float4*)(xs1 + (size_t)(row0 + r0 + i) * HID + c0) = v;
        }
    }
}

// ---------------------------------------------------------------------------
// edge weights: w = exp(leaky_relu(as1[src]+ad1[dst])); s1[dst] += w
// (no max-subtraction: logits are O(1) here, exp is safe in f32; ratio identical)
// ---------------------------------------------------------------------------
__global__ __launch_bounds__(256) void edge_w_kernel(
    const float* __restrict__ as1, const float* __restrict__ ad1,
    const int* __restrict__ src, const int* __restrict__ dst,
    float* __restrict__ we, float* __restrict__ s1, int E)
{
    int e = blockIdx.x * 256 + threadIdx.x;
    if (e >= E) return;
    int s = src[e], d = dst[e];
    float v = as1[s] + ad1[d];
    v = v > 0.f ? v : NEG_SLOPE * v;
    float w = __expf(v);
    we[e] = w;
    atomicAdd(&s1[d], w);
}

// ---------------------------------------------------------------------------
// aggregate: agg[dst,:] += w_e * xs[src,:]   (128 threads per edge, 2 edges/block)
// ---------------------------------------------------------------------------
__global__ __launch_bounds__(256) void aggregate_kernel(
    const float* __restrict__ xs, const float* __restrict__ we,
    const int* __restrict__ src, const int* __restrict__ dst,
    float* __restrict__ agg, int E)
{
    int g = blockIdx.x * 2 + (threadIdx.x >> 7);
    if (g >= E) return;
    int c = threadIdx.x & 127;
    int s = src[g], d = dst[g];
    float w = we[g];
    atomicAdd(&agg[(size_t)d * HID + c], w * xs[(size_t)s * HID + c]);
}

// ---------------------------------------------------------------------------
// epilogue: B = elu(B / s1)   in-place, float4
// ---------------------------------------------------------------------------
__global__ __launch_bounds__(256) void eludiv_kernel(
    float* __restrict__ B, const float* __restrict__ s1, int N)
{
    int i = blockIdx.x * 256 + threadIdx.x;       // float4 index
    int total4 = N * (HID / 4);
    if (i >= total4) return;
    int n = i >> 5;                               // (i*4) / 128
    float s = s1[n];
    float inv = s > 0.f ? 1.0f / s : 0.f;
    float4 v = ((const float4*)B)[i];
    v.x *= inv; v.y *= inv; v.z *= inv; v.w *= inv;
    v.x = v.x > 0.f ? v.x : expm1f(v.x);
    v.y = v.y > 0.f ? v.y : expm1f(v.y);
    v.z = v.z > 0.f ? v.z : expm1f(v.z);
    v.w = v.w > 0.f ? v.w : expm1f(v.w);
    ((float4*)B)[i] = v;
}

// ---------------------------------------------------------------------------
// gemm2: h2 = h1 @ W2   [N,128]x[128,32] -> f32 out
// block 256: 32 rows/block, thread = (row, 4 cols)
// ---------------------------------------------------------------------------
__global__ __launch_bounds__(256) void gemm2_kernel(
    const float* __restrict__ h1, const float* __restrict__ W2,
    float* __restrict__ h2, int N)
{
    __shared__ float lh[32 * 129];    // pad -> conflict-free per-row reads
    const int tid = threadIdx.x;
    const int row0 = blockIdx.x * 32;
    const int nrows = min(32, N - row0);
    for (int i = tid; i < nrows * 32; i += 256) {
        int r = i >> 5, q = i & 31;
        float4 v = *(const float4*)(h1 + (size_t)(row0 + r) * HID + q * 4);
        float* d = &lh[r * 129 + q * 4];
        d[0] = v.x; d[1] = v.y; d[2] = v.z; d[3] = v.w;
    }
    __syncthreads();
    const int r = tid >> 3;
    const int c0 = (tid & 7) * 4;
    float a0 = 0, a1 = 0, a2 = 0, a3 = 0;
    for (int k = 0; k < HID; k++) {
        float h = lh[r * 129 + k];
        float4 w = *(const float4*)(W2 + k * OUTD + c0);
        a0 += h * w.x; a1 += h * w.y; a2 += h * w.z; a3 += h * w.w;
    }
    if (r < nrows) {
        float4 o; o.x = a0; o.y = a1; o.z = a2; o.w = a3;
        *(float4*)(h2 + (size_t)(row0 + r) * OUTD + c0) = o;
    }
}

// ---------------------------------------------------------------------------
// gemm3: xs3 = h2 @ W2^T  [N,32]x[32,128]  (W2T pre-transposed in ws)
// block 128 = 32 cg x 4 rg; 16 rows/block; 4x4 tile
// ---------------------------------------------------------------------------
__global__ __launch_bounds__(128) void gemm3_kernel(
    const float* __restrict__ h2, const float* __restrict__ W2T,
    float* __restrict__ xs3, int N)
{
    __shared__ float lh[16 * OUTD];   // 2 KB
    const int tid = threadIdx.x;
    const int row0 = blockIdx.x * 16;
    const int nrows = min(16, N - row0);
    for (int i = tid; i < nrows * (OUTD / 4); i += 128) {
        int r = i >> 3, q = i & 7;
        ((float4*)lh)[r * 8 + q] =
            *(const float4*)(h2 + (size_t)(row0 + r) * OUTD + q * 4);
    }
    __syncthreads();
    const int cg = tid & 31, rg = tid >> 5;
    const int c0 = cg * 4, r0 = rg * 4;
    float acc[4][4];
    #pragma unroll
    for (int i = 0; i < 4; i++)
        #pragma unroll
        for (int j = 0; j < 4; j++) acc[i][j] = 0.f;
    #pragma unroll
    for (int k = 0; k < OUTD; k++) {
        float4 w = *(const float4*)(W2T + k * HID + c0);
        #pragma unroll
        for (int i = 0; i < 4; i++) {
            float h = lh[(r0 + i) * OUTD + k];
            acc[i][0] += h * w.x; acc[i][1] += h * w.y;
            acc[i][2] += h * w.z; acc[i][3] += h * w.w;
        }
    }
    #pragma unroll
    for (int i = 0; i < 4; i++) {
        if (r0 + i < nrows) {
            float4 v; v.x = acc[i][0]; v.y = acc[i][1]; v.z = acc[i][2]; v.w = acc[i][3];
            *(float4*)(xs3 + (size_t)(row0 + r0 + i) * HID + c0) = v;
        }
    }
}

// ---------------------------------------------------------------------------
// gemm4: h4 = h3 @ W1^T  [N,128]x[128,256] -> f32 out (W1T pre-transposed)
// block 256 = 64 cg x 4 rg; 16 rows/block; 4x4 tile
// ---------------------------------------------------------------------------
__global__ __launch_bounds__(256) void gemm4_kernel(
    const float* __restrict__ h3, const float* __restrict__ W1T,
    float* __restrict__ h4, int N)
{
    __shared__ float lh[16 * HID];    // 8 KB
    const int tid = threadIdx.x;
    const int row0 = blockIdx.x * 16;
    const int nrows = min(16, N - row0);
    for (int i = tid; i < nrows * (HID / 4); i += 256) {
        int r = i >> 5, q = i & 31;
        ((float4*)lh)[r * 32 + q] =
            *(const float4*)(h3 + (size_t)(row0 + r) * HID + q * 4);
    }
    __syncthreads();
    const int cg = tid & 63, rg = tid >> 6;
    const int c0 = cg * 4, r0 = rg * 4;
    float acc[4][4];
    #pragma unroll
    for (int i = 0; i < 4; i++)
        #pragma unroll
        for (int j = 0; j < 4; j++) acc[i][j] = 0.f;
    for (int k = 0; k < HID; k++) {
        float4 w = *(const float4*)(W1T + k * IN_DIM + c0);
        #pragma unroll
        for (int i = 0; i < 4; i++) {
            float h = lh[(r0 + i) * HID + k];
            acc[i][0] += h * w.x; acc[i][1] += h * w.y;
            acc[i][2] += h * w.z; acc[i][3] += h * w.w;
        }
    }
    #pragma unroll
    for (int i = 0; i < 4; i++) {
        if (r0 + i < nrows) {
            float4 v; v.x = acc[i][0]; v.y = acc[i][1]; v.z = acc[i][2]; v.w = acc[i][3];
            *(float4*)(h4 + (size_t)(row0 + r0 + i) * IN_DIM + c0) = v;
        }
    }
}

// ---------------------------------------------------------------------------
// prep: W1T[k,c] = W1[c,k] (128x256 from 256x128); W2T[k,c] = W2[c,k] (32x128)
// ---------------------------------------------------------------------------
__global__ void prep_kernel(const float* __restrict__ W1, const float* __restrict__ W2,
                            float* __restrict__ W1T, float* __restrict__ W2T)
{
    int idx = blockIdx.x * 256 + threadIdx.x;
    if (idx < IN_DIM * HID) {
        int c = idx >> 7, k = idx & 127;          // W1 is [256,128]: row c, col k
        W1T[k * IN_DIM + c] = W1[idx];
    }
    int idx2 = idx - IN_DIM * HID;
    if (idx2 >= 0 && idx2 < HID * OUTD) {
        int c = idx2 >> 5, k = idx2 & 31;         // W2 is [128,32]: row c, col k
        W2T[k * HID + c] = W2[idx2];
    }
}

extern "C" void kernel_launch(void* const* d_in, const int* in_sizes, int n_in,
                              void* d_out, int out_size, void* d_ws, size_t ws_size,
                              hipStream_t stream)
{
    const float* x     = (const float*)d_in[0];
    const float* W1    = (const float*)d_in[1];
    const float* a_src = (const float*)d_in[2];
    const float* a_dst = (const float*)d_in[3];
    const float* W2    = (const float*)d_in[4];
    const int*   ei    = (const int*)d_in[5];

    const int N = in_sizes[0] / IN_DIM;
    const int E = in_sizes[5] / 2;
    const int* src = ei;
    const int* dst = ei + E;

    float* ws = (float*)d_ws;
    size_t offA   = 0;                              // xs1 then xs3   [N*128]
    size_t offB   = offA + (size_t)N * HID;         // agg/h1 then agg/h3 [N*128]
    size_t offS   = offB + (size_t)N * HID;         // s1 [N] (adjacent to B: one memset)
    size_t offWe  = offS + N;                       // w_edge [E]
    size_t offW1T = offWe + E;
    size_t offW2T = offW1T + (size_t)IN_DIM * HID;
    size_t offAs  = offW2T + (size_t)HID * OUTD;    // as1 [N]
    size_t offAd  = offAs + N;                      // ad1 [N]

    float* A   = ws + offA;
    float* Bb  = ws + offB;
    float* s1  = ws + offS;
    float* we  = ws + offWe;
    float* W1T = ws + offW1T;
    float* W2T = ws + offW2T;
    float* as1 = ws + offAs;
    float* ad1 = ws + offAd;

    float* h2 = (float*)d_out;                      // [N,32]
    float* h4 = h2 + (size_t)N * OUTD;              // [N,256]

    // zero agg buffer + s1 (contiguous)
    hipMemsetAsync(Bb, 0, ((size_t)N * HID + N) * sizeof(float), stream);

    prep_kernel<<<(IN_DIM * HID + HID * OUTD + 255) / 256, 256, 0, stream>>>(W1, W2, W1T, W2T);
    gemm1_kernel<<<(N + 15) / 16, 128, 0, stream>>>(x, W1, a_src, a_dst, A, as1, ad1, N);
    edge_w_kernel<<<(E + 255) / 256, 256, 0, stream>>>(as1, ad1, src, dst, we, s1, E);
    aggregate_kernel<<<(E + 1) / 2, 256, 0, stream>>>(A, we, src, dst, Bb, E);
    eludiv_kernel<<<(N * (HID / 4) + 255) / 256, 256, 0, stream>>>(Bb, s1, N);
    gemm2_kernel<<<(N + 31) / 32, 256, 0, stream>>>(Bb, W2, h2, N);
    gemm3_kernel<<<(N + 15) / 16, 128, 0, stream>>>(h2, W2T, A, N);
    hipMemsetAsync(Bb, 0, (size_t)N * HID * sizeof(float), stream);
    aggregate_kernel<<<(E + 1) / 2, 256, 0, stream>>>(A, we, src, dst, Bb, E);
    eludiv_kernel<<<(N * (HID / 4) + 255) / 256, 256, 0, stream>>>(Bb, s1, N);
    gemm4_kernel<<<(N + 15) / 16, 256, 0, stream>>>(Bb, W1T, h4, N);
}

// Round 3
// 927.970 us; speedup vs baseline: 2.1511x; 2.1511x over previous
//
#include <hip/hip_runtime.h>
#include <math.h>

#define IN_DIM 256
#define HID 128
#define OUTD 32
#define NEG_SLOPE 0.2f

// ---------------------------------------------------------------------------
// gemm1: xs1 = x @ W1  [N,256]x[256,128], fused as1 = xs1.a_src, ad1 = xs1.a_dst
// block 128 threads = 32 colgroups x 4 rowgroups; 16 rows/block; 4x4 reg tile
// ---------------------------------------------------------------------------
__global__ __launch_bounds__(128) void gemm1_kernel(
    const float* __restrict__ x, const float* __restrict__ W1,
    const float* __restrict__ a_src, const float* __restrict__ a_dst,
    float* __restrict__ xs1, float* __restrict__ as1, float* __restrict__ ad1, int N)
{
    __shared__ float lx[16 * IN_DIM];     // 16 KB
    const int tid = threadIdx.x;
    const int row0 = blockIdx.x * 16;
    const int nrows = min(16, N - row0);

    for (int i = tid; i < nrows * (IN_DIM / 4); i += 128) {
        int r = i >> 6, q = i & 63;
        ((float4*)lx)[r * 64 + q] =
            *(const float4*)(x + (size_t)(row0 + r) * IN_DIM + q * 4);
    }
    __syncthreads();

    const int cg = tid & 31, rg = tid >> 5;
    const int c0 = cg * 4, r0 = rg * 4;
    float acc[4][4];
    #pragma unroll
    for (int i = 0; i < 4; i++)
        #pragma unroll
        for (int j = 0; j < 4; j++) acc[i][j] = 0.f;

    for (int k = 0; k < IN_DIM; k++) {
        float4 w = *(const float4*)(W1 + k * HID + c0);
        #pragma unroll
        for (int i = 0; i < 4; i++) {
            float h = lx[(r0 + i) * IN_DIM + k];
            acc[i][0] += h * w.x; acc[i][1] += h * w.y;
            acc[i][2] += h * w.z; acc[i][3] += h * w.w;
        }
    }

    float4 as4 = *(const float4*)(a_src + c0);
    float4 ad4 = *(const float4*)(a_dst + c0);
    #pragma unroll
    for (int i = 0; i < 4; i++) {
        float vs = acc[i][0]*as4.x + acc[i][1]*as4.y + acc[i][2]*as4.z + acc[i][3]*as4.w;
        float vd = acc[i][0]*ad4.x + acc[i][1]*ad4.y + acc[i][2]*ad4.z + acc[i][3]*ad4.w;
        #pragma unroll
        for (int off = 16; off >= 1; off >>= 1) {
            vs += __shfl_down(vs, off, 32);
            vd += __shfl_down(vd, off, 32);
        }
        if (cg == 0 && (r0 + i) < nrows) {
            as1[row0 + r0 + i] = vs;
            ad1[row0 + r0 + i] = vd;
        }
    }

    #pragma unroll
    for (int i = 0; i < 4; i++) {
        if (r0 + i < nrows) {
            float4 v; v.x = acc[i][0]; v.y = acc[i][1]; v.z = acc[i][2]; v.w = acc[i][3];
            *(float4*)(xs1 + (size_t)(row0 + r0 + i) * HID + c0) = v;
        }
    }
}

// ---------------------------------------------------------------------------
// CSR build: histogram -> scan (3 kernels) -> scatter (fused edge-weight calc)
// ---------------------------------------------------------------------------
__global__ __launch_bounds__(256) void hist_kernel(
    const int* __restrict__ dst, int* __restrict__ deg, int E)
{
    int e = blockIdx.x * 256 + threadIdx.x;
    if (e < E) atomicAdd(&deg[dst[e]], 1);
}

// each block scans a 2048-elem chunk (256 threads x 8 contiguous)
__global__ __launch_bounds__(256) void scanA_kernel(
    const int* __restrict__ deg, int* __restrict__ tpre, int* __restrict__ bsum, int N)
{
    __shared__ int lds[256];
    int b = blockIdx.x, t = threadIdx.x;
    int base = b * 2048 + t * 8;
    int s = 0;
    #pragma unroll
    for (int j = 0; j < 8; j++) { int i = base + j; s += (i < N) ? deg[i] : 0; }
    lds[t] = s;
    __syncthreads();
    for (int off = 1; off < 256; off <<= 1) {
        int v = (t >= off) ? lds[t - off] : 0;
        __syncthreads();
        lds[t] += v;
        __syncthreads();
    }
    tpre[b * 256 + t] = lds[t] - s;          // exclusive prefix within block
    if (t == 255) bsum[b] = lds[255];
}

__global__ void scanB_kernel(const int* __restrict__ bsum, int* __restrict__ bpre, int GA)
{
    if (threadIdx.x == 0) {
        int acc = 0;
        for (int i = 0; i < GA; i++) { bpre[i] = acc; acc += bsum[i]; }
    }
}

__global__ __launch_bounds__(256) void scanC_kernel(
    const int* __restrict__ deg, const int* __restrict__ tpre,
    const int* __restrict__ bpre, int* __restrict__ off, int* __restrict__ cur,
    int N, int E)
{
    int b = blockIdx.x, t = threadIdx.x;
    int base = b * 2048 + t * 8;
    int p = bpre[b] + tpre[b * 256 + t];
    #pragma unroll
    for (int j = 0; j < 8; j++) {
        int i = base + j;
        if (i < N) { off[i] = p; cur[i] = p; p += deg[i]; }
    }
    if (b == 0 && t == 0) off[N] = E;
}

__global__ __launch_bounds__(256) void scatter_kernel(
    const int* __restrict__ src, const int* __restrict__ dst,
    const float* __restrict__ as1, const float* __restrict__ ad1,
    int* __restrict__ cur, int* __restrict__ esrc, float* __restrict__ ew, int E)
{
    int e = blockIdx.x * 256 + threadIdx.x;
    if (e >= E) return;
    int s = src[e], d = dst[e];
    float v = as1[s] + ad1[d];
    v = v > 0.f ? v : NEG_SLOPE * v;
    float w = __expf(v);          // no max-subtraction: logits are O(1); ratio identical
    int pos = atomicAdd(&cur[d], 1);
    esrc[pos] = s;
    ew[pos] = w;
}

// ---------------------------------------------------------------------------
// pull-aggregate over CSR: one 64-lane wave per dst; lane = 2 feature cols.
// out[d,:] = elu( (sum_e w_e * xs[src_e,:]) / (sum_e w_e) ), single write, no atomics
// ---------------------------------------------------------------------------
__global__ __launch_bounds__(256) void agg_csr_kernel(
    const float* __restrict__ xs, const int* __restrict__ off,
    const int* __restrict__ esrc, const float* __restrict__ ew,
    float* __restrict__ out, int N)
{
    int d = blockIdx.x * 4 + (threadIdx.x >> 6);
    if (d >= N) return;
    int lane = threadIdx.x & 63;
    int e0 = off[d], e1 = off[d + 1];

    float ax = 0.f, ay = 0.f, s = 0.f;
    int e = e0;
    for (; e + 1 < e1; e += 2) {
        int s0 = esrc[e], s1i = esrc[e + 1];
        float w0 = ew[e], w1 = ew[e + 1];
        float2 v0 = *(const float2*)(xs + (size_t)s0 * HID + lane * 2);
        float2 v1 = *(const float2*)(xs + (size_t)s1i * HID + lane * 2);
        ax += w0 * v0.x + w1 * v1.x;
        ay += w0 * v0.y + w1 * v1.y;
        s += w0 + w1;
    }
    if (e < e1) {
        int s0 = esrc[e];
        float w0 = ew[e];
        float2 v0 = *(const float2*)(xs + (size_t)s0 * HID + lane * 2);
        ax += w0 * v0.x; ay += w0 * v0.y; s += w0;
    }

    float inv = s > 0.f ? 1.0f / s : 0.f;
    ax *= inv; ay *= inv;
    ax = ax > 0.f ? ax : expm1f(ax);
    ay = ay > 0.f ? ay : expm1f(ay);
    float2 o; o.x = ax; o.y = ay;
    *(float2*)(out + (size_t)d * HID + lane * 2) = o;
}

// ---------------------------------------------------------------------------
// gemm2: h2 = h1 @ W2   [N,128]x[128,32]
// ---------------------------------------------------------------------------
__global__ __launch_bounds__(256) void gemm2_kernel(
    const float* __restrict__ h1, const float* __restrict__ W2,
    float* __restrict__ h2, int N)
{
    __shared__ float lh[32 * 129];
    const int tid = threadIdx.x;
    const int row0 = blockIdx.x * 32;
    const int nrows = min(32, N - row0);
    for (int i = tid; i < nrows * 32; i += 256) {
        int r = i >> 5, q = i & 31;
        float4 v = *(const float4*)(h1 + (size_t)(row0 + r) * HID + q * 4);
        float* d = &lh[r * 129 + q * 4];
        d[0] = v.x; d[1] = v.y; d[2] = v.z; d[3] = v.w;
    }
    __syncthreads();
    const int r = tid >> 3;
    const int c0 = (tid & 7) * 4;
    float a0 = 0, a1 = 0, a2 = 0, a3 = 0;
    for (int k = 0; k < HID; k++) {
        float h = lh[r * 129 + k];
        float4 w = *(const float4*)(W2 + k * OUTD + c0);
        a0 += h * w.x; a1 += h * w.y; a2 += h * w.z; a3 += h * w.w;
    }
    if (r < nrows) {
        float4 o; o.x = a0; o.y = a1; o.z = a2; o.w = a3;
        *(float4*)(h2 + (size_t)(row0 + r) * OUTD + c0) = o;
    }
}

// ---------------------------------------------------------------------------
// gemm3: xs3 = h2 @ W2^T  [N,32]x[32,128]
// ---------------------------------------------------------------------------
__global__ __launch_bounds__(128) void gemm3_kernel(
    const float* __restrict__ h2, const float* __restrict__ W2T,
    float* __restrict__ xs3, int N)
{
    __shared__ float lh[16 * OUTD];
    const int tid = threadIdx.x;
    const int row0 = blockIdx.x * 16;
    const int nrows = min(16, N - row0);
    for (int i = tid; i < nrows * (OUTD / 4); i += 128) {
        int r = i >> 3, q = i & 7;
        ((float4*)lh)[r * 8 + q] =
            *(const float4*)(h2 + (size_t)(row0 + r) * OUTD + q * 4);
    }
    __syncthreads();
    const int cg = tid & 31, rg = tid >> 5;
    const int c0 = cg * 4, r0 = rg * 4;
    float acc[4][4];
    #pragma unroll
    for (int i = 0; i < 4; i++)
        #pragma unroll
        for (int j = 0; j < 4; j++) acc[i][j] = 0.f;
    #pragma unroll
    for (int k = 0; k < OUTD; k++) {
        float4 w = *(const float4*)(W2T + k * HID + c0);
        #pragma unroll
        for (int i = 0; i < 4; i++) {
            float h = lh[(r0 + i) * OUTD + k];
            acc[i][0] += h * w.x; acc[i][1] += h * w.y;
            acc[i][2] += h * w.z; acc[i][3] += h * w.w;
        }
    }
    #pragma unroll
    for (int i = 0; i < 4; i++) {
        if (r0 + i < nrows) {
            float4 v; v.x = acc[i][0]; v.y = acc[i][1]; v.z = acc[i][2]; v.w = acc[i][3];
            *(float4*)(xs3 + (size_t)(row0 + r0 + i) * HID + c0) = v;
        }
    }
}

// ---------------------------------------------------------------------------
// gemm4: h4 = h3 @ W1^T  [N,128]x[128,256]
// ---------------------------------------------------------------------------
__global__ __launch_bounds__(256) void gemm4_kernel(
    const float* __restrict__ h3, const float* __restrict__ W1T,
    float* __restrict__ h4, int N)
{
    __shared__ float lh[16 * HID];
    const int tid = threadIdx.x;
    const int row0 = blockIdx.x * 16;
    const int nrows = min(16, N - row0);
    for (int i = tid; i < nrows * (HID / 4); i += 256) {
        int r = i >> 5, q = i & 31;
        ((float4*)lh)[r * 32 + q] =
            *(const float4*)(h3 + (size_t)(row0 + r) * HID + q * 4);
    }
    __syncthreads();
    const int cg = tid & 63, rg = tid >> 6;
    const int c0 = cg * 4, r0 = rg * 4;
    float acc[4][4];
    #pragma unroll
    for (int i = 0; i < 4; i++)
        #pragma unroll
        for (int j = 0; j < 4; j++) acc[i][j] = 0.f;
    for (int k = 0; k < HID; k++) {
        float4 w = *(const float4*)(W1T + k * IN_DIM + c0);
        #pragma unroll
        for (int i = 0; i < 4; i++) {
            float h = lh[(r0 + i) * HID + k];
            acc[i][0] += h * w.x; acc[i][1] += h * w.y;
            acc[i][2] += h * w.z; acc[i][3] += h * w.w;
        }
    }
    #pragma unroll
    for (int i = 0; i < 4; i++) {
        if (r0 + i < nrows) {
            float4 v; v.x = acc[i][0]; v.y = acc[i][1]; v.z = acc[i][2]; v.w = acc[i][3];
            *(float4*)(h4 + (size_t)(row0 + r0 + i) * IN_DIM + c0) = v;
        }
    }
}

// ---------------------------------------------------------------------------
// prep: W1T[k,c] = W1[c,k]; W2T[k,c] = W2[c,k]
// ---------------------------------------------------------------------------
__global__ void prep_kernel(const float* __restrict__ W1, const float* __restrict__ W2,
                            float* __restrict__ W1T, float* __restrict__ W2T)
{
    int idx = blockIdx.x * 256 + threadIdx.x;
    if (idx < IN_DIM * HID) {
        int c = idx >> 7, k = idx & 127;
        W1T[k * IN_DIM + c] = W1[idx];
    }
    int idx2 = idx - IN_DIM * HID;
    if (idx2 >= 0 && idx2 < HID * OUTD) {
        int c = idx2 >> 5, k = idx2 & 31;
        W2T[k * HID + c] = W2[idx2];
    }
}

extern "C" void kernel_launch(void* const* d_in, const int* in_sizes, int n_in,
                              void* d_out, int out_size, void* d_ws, size_t ws_size,
                              hipStream_t stream)
{
    const float* x     = (const float*)d_in[0];
    const float* W1    = (const float*)d_in[1];
    const float* a_src = (const float*)d_in[2];
    const float* a_dst = (const float*)d_in[3];
    const float* W2    = (const float*)d_in[4];
    const int*   ei    = (const int*)d_in[5];

    const int N = in_sizes[0] / IN_DIM;
    const int E = in_sizes[5] / 2;
    const int* src = ei;
    const int* dst = ei + E;
    const int GA = (N + 2047) / 2048;     // scan chunks

    float* ws = (float*)d_ws;
    size_t o = 0;
    float* A   = ws + o; o += (size_t)N * HID;        // xs1 / xs3
    float* Bb  = ws + o; o += (size_t)N * HID;        // h1 / h3
    float* as1 = ws + o; o += N;
    float* ad1 = ws + o; o += N;
    float* ew  = ws + o; o += E;                      // sorted edge weights
    float* W1T = ws + o; o += (size_t)IN_DIM * HID;
    float* W2T = ws + o; o += (size_t)HID * OUTD;
    int* ibase = (int*)(ws + o);
    int* deg  = ibase;              // N
    int* off  = deg + N;            // N+1
    int* cur  = off + N + 1;        // N
    int* esrc = cur + N;            // E (sorted src)
    int* tpre = esrc + E;           // GA*256
    int* bsum = tpre + (size_t)GA * 256;  // GA
    int* bpre = bsum + GA;          // GA

    float* h2 = (float*)d_out;                 // [N,32]
    float* h4 = h2 + (size_t)N * OUTD;         // [N,256]

    hipMemsetAsync(deg, 0, (size_t)N * sizeof(int), stream);

    prep_kernel<<<(IN_DIM * HID + HID * OUTD + 255) / 256, 256, 0, stream>>>(W1, W2, W1T, W2T);
    gemm1_kernel<<<(N + 15) / 16, 128, 0, stream>>>(x, W1, a_src, a_dst, A, as1, ad1, N);

    // CSR build (counting sort by dst), edge weights fused into scatter
    hist_kernel<<<(E + 255) / 256, 256, 0, stream>>>(dst, deg, E);
    scanA_kernel<<<GA, 256, 0, stream>>>(deg, tpre, bsum, N);
    scanB_kernel<<<1, 64, 0, stream>>>(bsum, bpre, GA);
    scanC_kernel<<<GA, 256, 0, stream>>>(deg, tpre, bpre, off, cur, N, E);
    scatter_kernel<<<(E + 255) / 256, 256, 0, stream>>>(src, dst, as1, ad1, cur, esrc, ew, E);

    // conv1 aggregate (fused /s + elu), then gemm2
    agg_csr_kernel<<<(N + 3) / 4, 256, 0, stream>>>(A, off, esrc, ew, Bb, N);
    gemm2_kernel<<<(N + 31) / 32, 256, 0, stream>>>(Bb, W2, h2, N);

    // conv3 with tied attention: gemm3, aggregate (same CSR), gemm4
    gemm3_kernel<<<(N + 15) / 16, 128, 0, stream>>>(h2, W2T, A, N);
    agg_csr_kernel<<<(N + 3) / 4, 256, 0, stream>>>(A, off, esrc, ew, Bb, N);
    gemm4_kernel<<<(N + 15) / 16, 256, 0, stream>>>(Bb, W1T, h4, N);
}

// Round 4
// 751.586 us; speedup vs baseline: 2.6559x; 1.2347x over previous
//
#include <hip/hip_runtime.h>
#include <math.h>

#define IN_DIM 256
#define HID 128
#define OUTD 32
#define NEG_SLOPE 0.2f

typedef unsigned short ushort_t;
typedef unsigned int uint_t;
typedef __attribute__((ext_vector_type(8))) short short8;
typedef __attribute__((ext_vector_type(4))) float f32x4;

__device__ __forceinline__ ushort_t f2b(float f) {
    union { float f; uint_t i; } v; v.f = f;
    uint_t x = v.i;
    uint_t r = (x + 0x7FFFu + ((x >> 16) & 1u)) >> 16;   // RNE
    return (ushort_t)r;
}

// ---------------------------------------------------------------------------
// convert x -> bf16 (8 elems/thread, 16B stores)
// ---------------------------------------------------------------------------
__global__ __launch_bounds__(256) void cvtx_kernel(
    const float* __restrict__ x, ushort_t* __restrict__ xb, int total8)
{
    int i = blockIdx.x * 256 + threadIdx.x;
    if (i >= total8) return;
    float4 v0 = *(const float4*)(x + (size_t)i * 8);
    float4 v1 = *(const float4*)(x + (size_t)i * 8 + 4);
    ushort_t o[8] = { f2b(v0.x), f2b(v0.y), f2b(v0.z), f2b(v0.w),
                      f2b(v1.x), f2b(v1.y), f2b(v1.z), f2b(v1.w) };
    *(uint4*)(xb + (size_t)i * 8) = *(uint4*)o;
}

// ---------------------------------------------------------------------------
// swizzle weights into MFMA B-fragment order (bf16).
// B-frag layout for 16x16x32: lane l holds B[k][n], n=16*tile+(l&15), k=32*step+(l>>4)*8+j
// W1B : B=W1   [K=256][N=128] -> 8 steps x 8 tiles
// W1TB: B=W1^T [K=128][N=256] -> 4 steps x 16 tiles   (W1T[k][n] = W1[n][k])
// W2TB: B=W2^T [K=32][N=128]  -> 1 step  x 8 tiles    (W2T[k][n] = W2[n][k])
// ---------------------------------------------------------------------------
__global__ __launch_bounds__(256) void swz_kernel(
    const float* __restrict__ W1, const float* __restrict__ W2,
    ushort_t* __restrict__ W1B, ushort_t* __restrict__ W1TB, ushort_t* __restrict__ W2TB)
{
    int idx = blockIdx.x * 256 + threadIdx.x;
    if (idx < 32768) {
        int j = idx & 7, l = (idx >> 3) & 63, t = (idx >> 9) & 7, s = idx >> 12;
        int n = 16 * t + (l & 15), k = 32 * s + (l >> 4) * 8 + j;
        W1B[idx] = f2b(W1[k * HID + n]);
    } else if (idx < 65536) {
        int o = idx - 32768;
        int j = o & 7, l = (o >> 3) & 63, t = (o >> 9) & 15, s = o >> 13;
        int n = 16 * t + (l & 15), k = 32 * s + (l >> 4) * 8 + j;
        W1TB[o] = f2b(W1[n * HID + k]);
    } else if (idx < 69632) {
        int o = idx - 65536;
        int j = o & 7, l = (o >> 3) & 63, t = o >> 9;
        int n = 16 * t + (l & 15), k = (l >> 4) * 8 + j;
        W2TB[o] = f2b(W2[n * OUTD + k]);
    }
}

// ---------------------------------------------------------------------------
// gemm1 (MFMA): xs1 = x @ W1 [N,256]x[256,128] + fused as1/ad1 attention dots.
// block 256 = 4 waves; 64 rows x 128 cols per block; wave w: rows 16w..16w+15.
// ---------------------------------------------------------------------------
__global__ __launch_bounds__(256) void gemm1_mfma(
    const ushort_t* __restrict__ xb, const ushort_t* __restrict__ W1B,
    const float* __restrict__ a_src, const float* __restrict__ a_dst,
    float* __restrict__ xs1, float* __restrict__ as1, float* __restrict__ ad1, int N)
{
    __shared__ ushort_t lx[64 * 264];          // 256+8 pad: 2-way bank alias only
    const int tid = threadIdx.x;
    const int row0 = blockIdx.x * 64;
    const int nrows = min(64, N - row0);

    for (int i = tid; i < nrows * 32; i += 256) {
        int r = i >> 5, c = i & 31;
        *(uint4*)(&lx[r * 264 + c * 8]) =
            *(const uint4*)(xb + (size_t)(row0 + r) * IN_DIM + c * 8);
    }
    __syncthreads();

    const int wave = tid >> 6, lane = tid & 63;
    const int lo = lane & 15, q = lane >> 4;
    f32x4 acc[8];
    #pragma unroll
    for (int t = 0; t < 8; t++) acc[t] = (f32x4){0.f, 0.f, 0.f, 0.f};

    const int arow = wave * 16 + lo;
    #pragma unroll
    for (int s = 0; s < 8; s++) {
        short8 af = *(const short8*)(&lx[arow * 264 + s * 32 + q * 8]);
        #pragma unroll
        for (int t = 0; t < 8; t++) {
            short8 bf = *(const short8*)(W1B + ((size_t)(s * 8 + t) * 64 + lane) * 8);
            acc[t] = __builtin_amdgcn_mfma_f32_16x16x32_bf16(af, bf, acc[t], 0, 0, 0);
        }
    }

    // attention logits: vs[m] = sum_n xs1[m][n]*a_src[n].  C layout: row=q*4+r, col=lo.
    float asv[8], adv[8];
    #pragma unroll
    for (int t = 0; t < 8; t++) { asv[t] = a_src[t * 16 + lo]; adv[t] = a_dst[t * 16 + lo]; }
    #pragma unroll
    for (int r = 0; r < 4; r++) {
        float vs = 0.f, vd = 0.f;
        #pragma unroll
        for (int t = 0; t < 8; t++) { vs += acc[t][r] * asv[t]; vd += acc[t][r] * adv[t]; }
        #pragma unroll
        for (int off = 1; off < 16; off <<= 1) {       // reduce over lo (stays in q-group)
            vs += __shfl_xor(vs, off, 64);
            vd += __shfl_xor(vd, off, 64);
        }
        int m = row0 + wave * 16 + q * 4 + r;
        if (lo == 0 && m < N) { as1[m] = vs; ad1[m] = vd; }
    }

    #pragma unroll
    for (int r = 0; r < 4; r++) {
        int m = row0 + wave * 16 + q * 4 + r;
        if (m < N) {
            #pragma unroll
            for (int t = 0; t < 8; t++)
                xs1[(size_t)m * HID + t * 16 + lo] = acc[t][r];
        }
    }
}

// ---------------------------------------------------------------------------
// gemm3 (MFMA): xs3 = h2 @ W2^T [N,32]x[32,128]; K=32 -> single step
// ---------------------------------------------------------------------------
__global__ __launch_bounds__(256) void gemm3_mfma(
    const ushort_t* __restrict__ h2b, const ushort_t* __restrict__ W2TB,
    float* __restrict__ xs3, int N)
{
    __shared__ ushort_t lh[64 * 40];           // 32+8 pad
    const int tid = threadIdx.x;
    const int row0 = blockIdx.x * 64;
    const int nrows = min(64, N - row0);
    for (int i = tid; i < nrows * 4; i += 256) {
        int r = i >> 2, c = i & 3;
        *(uint4*)(&lh[r * 40 + c * 8]) =
            *(const uint4*)(h2b + (size_t)(row0 + r) * OUTD + c * 8);
    }
    __syncthreads();

    const int wave = tid >> 6, lane = tid & 63;
    const int lo = lane & 15, q = lane >> 4;
    f32x4 acc[8];
    #pragma unroll
    for (int t = 0; t < 8; t++) acc[t] = (f32x4){0.f, 0.f, 0.f, 0.f};
    short8 af = *(const short8*)(&lh[(wave * 16 + lo) * 40 + q * 8]);
    #pragma unroll
    for (int t = 0; t < 8; t++) {
        short8 bf = *(const short8*)(W2TB + ((size_t)t * 64 + lane) * 8);
        acc[t] = __builtin_amdgcn_mfma_f32_16x16x32_bf16(af, bf, acc[t], 0, 0, 0);
    }
    #pragma unroll
    for (int r = 0; r < 4; r++) {
        int m = row0 + wave * 16 + q * 4 + r;
        if (m < N) {
            #pragma unroll
            for (int t = 0; t < 8; t++)
                xs3[(size_t)m * HID + t * 16 + lo] = acc[t][r];
        }
    }
}

// ---------------------------------------------------------------------------
// gemm4 (MFMA): h4 = h3 @ W1^T [N,128]x[128,256]
// ---------------------------------------------------------------------------
__global__ __launch_bounds__(256) void gemm4_mfma(
    const ushort_t* __restrict__ h3b, const ushort_t* __restrict__ W1TB,
    float* __restrict__ h4, int N)
{
    __shared__ ushort_t lh[64 * 136];          // 128+8 pad
    const int tid = threadIdx.x;
    const int row0 = blockIdx.x * 64;
    const int nrows = min(64, N - row0);
    for (int i = tid; i < nrows * 16; i += 256) {
        int r = i >> 4, c = i & 15;
        *(uint4*)(&lh[r * 136 + c * 8]) =
            *(const uint4*)(h3b + (size_t)(row0 + r) * HID + c * 8);
    }
    __syncthreads();

    const int wave = tid >> 6, lane = tid & 63;
    const int lo = lane & 15, q = lane >> 4;
    f32x4 acc[16];
    #pragma unroll
    for (int t = 0; t < 16; t++) acc[t] = (f32x4){0.f, 0.f, 0.f, 0.f};
    const int arow = wave * 16 + lo;
    #pragma unroll
    for (int s = 0; s < 4; s++) {
        short8 af = *(const short8*)(&lh[arow * 136 + s * 32 + q * 8]);
        #pragma unroll
        for (int t = 0; t < 16; t++) {
            short8 bf = *(const short8*)(W1TB + ((size_t)(s * 16 + t) * 64 + lane) * 8);
            acc[t] = __builtin_amdgcn_mfma_f32_16x16x32_bf16(af, bf, acc[t], 0, 0, 0);
        }
    }
    #pragma unroll
    for (int r = 0; r < 4; r++) {
        int m = row0 + wave * 16 + q * 4 + r;
        if (m < N) {
            #pragma unroll
            for (int t = 0; t < 16; t++)
                h4[(size_t)m * IN_DIM + t * 16 + lo] = acc[t][r];
        }
    }
}

// ---------------------------------------------------------------------------
// CSR build: histogram -> scan -> scatter (fused edge-weight calc)
// ---------------------------------------------------------------------------
__global__ __launch_bounds__(256) void hist_kernel(
    const int* __restrict__ dst, int* __restrict__ deg, int E)
{
    int e = blockIdx.x * 256 + threadIdx.x;
    if (e < E) atomicAdd(&deg[dst[e]], 1);
}

__global__ __launch_bounds__(256) void scanA_kernel(
    const int* __restrict__ deg, int* __restrict__ tpre, int* __restrict__ bsum, int N)
{
    __shared__ int lds[256];
    int b = blockIdx.x, t = threadIdx.x;
    int base = b * 2048 + t * 8;
    int s = 0;
    #pragma unroll
    for (int j = 0; j < 8; j++) { int i = base + j; s += (i < N) ? deg[i] : 0; }
    lds[t] = s;
    __syncthreads();
    for (int off = 1; off < 256; off <<= 1) {
        int v = (t >= off) ? lds[t - off] : 0;
        __syncthreads();
        lds[t] += v;
        __syncthreads();
    }
    tpre[b * 256 + t] = lds[t] - s;
    if (t == 255) bsum[b] = lds[255];
}

__global__ void scanB_kernel(const int* __restrict__ bsum, int* __restrict__ bpre, int GA)
{
    if (threadIdx.x == 0) {
        int acc = 0;
        for (int i = 0; i < GA; i++) { bpre[i] = acc; acc += bsum[i]; }
    }
}

__global__ __launch_bounds__(256) void scanC_kernel(
    const int* __restrict__ deg, const int* __restrict__ tpre,
    const int* __restrict__ bpre, int* __restrict__ off, int* __restrict__ cur,
    int N, int E)
{
    int b = blockIdx.x, t = threadIdx.x;
    int base = b * 2048 + t * 8;
    int p = bpre[b] + tpre[b * 256 + t];
    #pragma unroll
    for (int j = 0; j < 8; j++) {
        int i = base + j;
        if (i < N) { off[i] = p; cur[i] = p; p += deg[i]; }
    }
    if (b == 0 && t == 0) off[N] = E;
}

__global__ __launch_bounds__(256) void scatter_kernel(
    const int* __restrict__ src, const int* __restrict__ dst,
    const float* __restrict__ as1, const float* __restrict__ ad1,
    int* __restrict__ cur, int* __restrict__ esrc, float* __restrict__ ew, int E)
{
    int e = blockIdx.x * 256 + threadIdx.x;
    if (e >= E) return;
    int s = src[e], d = dst[e];
    float v = as1[s] + ad1[d];
    v = v > 0.f ? v : NEG_SLOPE * v;
    float w = __expf(v);          // no max-subtraction: logits O(1); softmax ratio identical
    int pos = atomicAdd(&cur[d], 1);
    esrc[pos] = s;
    ew[pos] = w;
}

// ---------------------------------------------------------------------------
// pull-aggregate over CSR: wave per dst, lane = 2 feature cols; fused /s + elu.
// BOUT: write bf16 (for gemm4 input) instead of f32.
// ---------------------------------------------------------------------------
template<bool BOUT>
__global__ __launch_bounds__(256) void agg_csr_kernel(
    const float* __restrict__ xs, const int* __restrict__ off,
    const int* __restrict__ esrc, const float* __restrict__ ew,
    float* __restrict__ outf, ushort_t* __restrict__ outb, int N)
{
    int d = blockIdx.x * 4 + (threadIdx.x >> 6);
    if (d >= N) return;
    int lane = threadIdx.x & 63;
    int e0 = off[d], e1 = off[d + 1];

    float ax = 0.f, ay = 0.f, s = 0.f;
    int e = e0;
    for (; e + 1 < e1; e += 2) {
        int s0 = esrc[e], s1i = esrc[e + 1];
        float w0 = ew[e], w1 = ew[e + 1];
        float2 v0 = *(const float2*)(xs + (size_t)s0 * HID + lane * 2);
        float2 v1 = *(const float2*)(xs + (size_t)s1i * HID + lane * 2);
        ax += w0 * v0.x + w1 * v1.x;
        ay += w0 * v0.y + w1 * v1.y;
        s += w0 + w1;
    }
    if (e < e1) {
        int s0 = esrc[e];
        float w0 = ew[e];
        float2 v0 = *(const float2*)(xs + (size_t)s0 * HID + lane * 2);
        ax += w0 * v0.x; ay += w0 * v0.y; s += w0;
    }

    float inv = s > 0.f ? 1.0f / s : 0.f;
    ax *= inv; ay *= inv;
    ax = ax > 0.f ? ax : expm1f(ax);
    ay = ay > 0.f ? ay : expm1f(ay);
    if (BOUT) {
        ushort2 o; o.x = f2b(ax); o.y = f2b(ay);
        *(ushort2*)(outb + (size_t)d * HID + lane * 2) = o;
    } else {
        float2 o; o.x = ax; o.y = ay;
        *(float2*)(outf + (size_t)d * HID + lane * 2) = o;
    }
}

// ---------------------------------------------------------------------------
// gemm2: h2 = h1 @ W2 [N,128]x[128,32], f32 (accuracy) + bf16 copy for gemm3
// ---------------------------------------------------------------------------
__global__ __launch_bounds__(256) void gemm2_kernel(
    const float* __restrict__ h1, const float* __restrict__ W2,
    float* __restrict__ h2, ushort_t* __restrict__ h2b, int N)
{
    __shared__ float lh[32 * 129];
    const int tid = threadIdx.x;
    const int row0 = blockIdx.x * 32;
    const int nrows = min(32, N - row0);
    for (int i = tid; i < nrows * 32; i += 256) {
        int r = i >> 5, q = i & 31;
        float4 v = *(const float4*)(h1 + (size_t)(row0 + r) * HID + q * 4);
        float* d = &lh[r * 129 + q * 4];
        d[0] = v.x; d[1] = v.y; d[2] = v.z; d[3] = v.w;
    }
    __syncthreads();
    const int r = tid >> 3;
    const int c0 = (tid & 7) * 4;
    float a0 = 0, a1 = 0, a2 = 0, a3 = 0;
    for (int k = 0; k < HID; k++) {
        float h = lh[r * 129 + k];
        float4 w = *(const float4*)(W2 + k * OUTD + c0);
        a0 += h * w.x; a1 += h * w.y; a2 += h * w.z; a3 += h * w.w;
    }
    if (r < nrows) {
        float4 o; o.x = a0; o.y = a1; o.z = a2; o.w = a3;
        *(float4*)(h2 + (size_t)(row0 + r) * OUTD + c0) = o;
        ushort_t ob[4] = { f2b(a0), f2b(a1), f2b(a2), f2b(a3) };
        *(uint2*)(h2b + (size_t)(row0 + r) * OUTD + c0) = *(uint2*)ob;
    }
}

extern "C" void kernel_launch(void* const* d_in, const int* in_sizes, int n_in,
                              void* d_out, int out_size, void* d_ws, size_t ws_size,
                              hipStream_t stream)
{
    const float* x     = (const float*)d_in[0];
    const float* W1    = (const float*)d_in[1];
    const float* a_src = (const float*)d_in[2];
    const float* a_dst = (const float*)d_in[3];
    const float* W2    = (const float*)d_in[4];
    const int*   ei    = (const int*)d_in[5];

    const int N = in_sizes[0] / IN_DIM;
    const int E = in_sizes[5] / 2;
    const int* src = ei;
    const int* dst = ei + E;
    const int GA = (N + 2047) / 2048;

    float* ws = (float*)d_ws;
    size_t o = 0;
    float* A   = ws + o; o += (size_t)N * HID;        // xs1 / xs3 (f32)
    float* Bb  = ws + o; o += (size_t)N * HID;        // h1 (f32); also aliased as xb
    float* as1 = ws + o; o += N;
    float* ad1 = ws + o; o += N;
    float* ew  = ws + o; o += E;
    ushort_t* h3b  = (ushort_t*)(ws + o); o += (size_t)N * HID / 2;   // bf16 h3
    ushort_t* h2b  = (ushort_t*)(ws + o); o += (size_t)N * OUTD / 2;  // bf16 h2
    ushort_t* W1B  = (ushort_t*)(ws + o); o += 16384;
    ushort_t* W1TB = (ushort_t*)(ws + o); o += 16384;
    ushort_t* W2TB = (ushort_t*)(ws + o); o += 2048;
    int* deg  = (int*)(ws + o);
    int* off  = deg + N;
    int* cur  = off + N + 1;
    int* esrc = cur + N;
    int* tpre = esrc + E;
    int* bsum = tpre + (size_t)GA * 256;
    int* bpre = bsum + GA;

    ushort_t* xb = (ushort_t*)Bb;   // bf16 x [N,256], dead before agg1 writes h1 into Bb

    float* h2 = (float*)d_out;                 // [N,32]
    float* h4 = h2 + (size_t)N * OUTD;         // [N,256]

    hipMemsetAsync(deg, 0, (size_t)N * sizeof(int), stream);

    cvtx_kernel<<<(N * IN_DIM / 8 + 255) / 256, 256, 0, stream>>>(x, xb, N * IN_DIM / 8);
    swz_kernel<<<(69632 + 255) / 256, 256, 0, stream>>>(W1, W2, W1B, W1TB, W2TB);

    gemm1_mfma<<<(N + 63) / 64, 256, 0, stream>>>(xb, W1B, a_src, a_dst, A, as1, ad1, N);

    // CSR build (counting sort by dst), edge weights fused into scatter
    hist_kernel<<<(E + 255) / 256, 256, 0, stream>>>(dst, deg, E);
    scanA_kernel<<<GA, 256, 0, stream>>>(deg, tpre, bsum, N);
    scanB_kernel<<<1, 64, 0, stream>>>(bsum, bpre, GA);
    scanC_kernel<<<GA, 256, 0, stream>>>(deg, tpre, bpre, off, cur, N, E);
    scatter_kernel<<<(E + 255) / 256, 256, 0, stream>>>(src, dst, as1, ad1, cur, esrc, ew, E);

    // conv1 aggregate -> h1 (f32), gemm2 -> h2 (f32 out) + h2b (bf16)
    agg_csr_kernel<false><<<(N + 3) / 4, 256, 0, stream>>>(A, off, esrc, ew, Bb, (ushort_t*)0, N);
    gemm2_kernel<<<(N + 31) / 32, 256, 0, stream>>>(Bb, W2, h2, h2b, N);

    // conv3 (tied attention): gemm3 -> xs3, aggregate -> h3b (bf16), gemm4 -> h4
    gemm3_mfma<<<(N + 63) / 64, 256, 0, stream>>>(h2b, W2TB, A, N);
    agg_csr_kernel<true><<<(N + 3) / 4, 256, 0, stream>>>(A, off, esrc, ew, (float*)0, h3b, N);
    gemm4_mfma<<<(N + 63) / 64, 256, 0, stream>>>(h3b, W1TB, h4, N);
}